// Round 5
// baseline (243.768 us; speedup 1.0000x reference)
//
#include <hip/hip_runtime.h>

// LIF recurrence, T=4, TAU=1.0, THRESH=1.0.
// mem = mem + x[t]; spike = (mem - 1 > 0); mem = spike ? 0 : mem.
//
// v4 (resubmit — round 4 bench was a broker timeout, kernel never ran):
// force deep memory-level parallelism. v3 intended a 4-8 deep load
// pipeline but the register allocator collapsed it (VGPR_Count=32 vs the
// >=48 the pipeline needs) — loads were re-sunk next to uses, ~2 in flight.
// All variants pin at 82-84us = 2.4 TB/s with VALUBusy 5%: classic
// congested-latency regime (in-flight bytes/CU ~64KB vs ~100KB needed when
// HBM latency inflates under load).
// Fix: batch ALL 16 loads (T=4 x CHUNKS=4 f32x4, 64 data VGPRs) up front,
// then __builtin_amdgcn_sched_barrier(0) so the scheduler cannot sink them.
// 16 KB in flight per wave; ~300 KB per CU at 5 waves/SIMD.
// NT stores kept (proven no-RFO: FETCH=65MB). Single variable vs v3: schedule.

#define LIF_T 4
#define CHUNKS 4

typedef float f32x4 __attribute__((ext_vector_type(4)));

__device__ __forceinline__ f32x4 lif_step(f32x4& mem, f32x4 xt) {
    mem.x += xt.x;
    mem.y += xt.y;
    mem.z += xt.z;
    mem.w += xt.w;
    f32x4 sp;
    sp.x = (mem.x > 1.0f) ? 1.0f : 0.0f;
    sp.y = (mem.y > 1.0f) ? 1.0f : 0.0f;
    sp.z = (mem.z > 1.0f) ? 1.0f : 0.0f;
    sp.w = (mem.w > 1.0f) ? 1.0f : 0.0f;
    mem.x = (sp.x > 0.f) ? 0.f : mem.x;
    mem.y = (sp.y > 0.f) ? 0.f : mem.y;
    mem.z = (sp.z > 0.f) ? 0.f : mem.z;
    mem.w = (sp.w > 0.f) ? 0.f : mem.w;
    return sp;
}

__global__ __launch_bounds__(256) void
lif_spike_kernel(const float* __restrict__ x, float* __restrict__ out,
                 int n_vec, int stride /* = total threads */) {
    const int tid0 = blockIdx.x * blockDim.x + threadIdx.x;
    const f32x4* __restrict__ xv = reinterpret_cast<const f32x4*>(x);
    f32x4* __restrict__ ov = reinterpret_cast<f32x4*>(out);

    if (tid0 + (CHUNKS - 1) * stride < n_vec) {
        // ---- fast path (whole grid in the exact bench shape) ----
        // Issue all 16 independent loads back-to-back.
        f32x4 v[LIF_T][CHUNKS];
#pragma unroll
        for (int t = 0; t < LIF_T; ++t)
#pragma unroll
            for (int c = 0; c < CHUNKS; ++c)
                v[t][c] = xv[(size_t)t * n_vec + tid0 + (size_t)c * stride];

        // Pin the schedule: nothing below may move above, loads may not sink.
        __builtin_amdgcn_sched_barrier(0);

        f32x4 mem[CHUNKS];
#pragma unroll
        for (int c = 0; c < CHUNKS; ++c) mem[c] = (f32x4){0.f, 0.f, 0.f, 0.f};

#pragma unroll
        for (int t = 0; t < LIF_T; ++t) {
#pragma unroll
            for (int c = 0; c < CHUNKS; ++c) {
                f32x4 sp = lif_step(mem[c], v[t][c]);
                __builtin_nontemporal_store(
                    sp, &ov[(size_t)t * n_vec + tid0 + (size_t)c * stride]);
            }
        }
    } else {
        // ---- tail path (never taken in the exact bench shape) ----
#pragma unroll
        for (int c = 0; c < CHUNKS; ++c) {
            int idx = tid0 + c * stride;
            if (idx >= n_vec) break;  // idx monotone in c
            f32x4 memc = (f32x4){0.f, 0.f, 0.f, 0.f};
#pragma unroll
            for (int t = 0; t < LIF_T; ++t) {
                f32x4 xt = xv[(size_t)t * n_vec + idx];
                f32x4 sp = lif_step(memc, xt);
                __builtin_nontemporal_store(sp, &ov[(size_t)t * n_vec + idx]);
            }
        }
    }
}

extern "C" void kernel_launch(void* const* d_in, const int* in_sizes, int n_in,
                              void* d_out, int out_size, void* d_ws, size_t ws_size,
                              hipStream_t stream) {
    const float* x = (const float*)d_in[0];
    float* out = (float*)d_out;

    int n = out_size / LIF_T;      // elements per timestep (8,388,608)
    int n_vec = n / 4;             // float4 groups per timestep (2,097,152)

    const int block = 256;
    int grid = (n_vec + block * CHUNKS - 1) / (block * CHUNKS);  // 2048
    int stride = grid * block;                                   // 524,288
    lif_spike_kernel<<<grid, block, 0, stream>>>(x, out, n_vec, stride);
}